// Round 7
// baseline (687.169 us; speedup 1.0000x reference)
//
#include <hip/hip_runtime.h>
#include <hip/hip_bf16.h>
#include <hip/hip_fp16.h>

#define B_ 2
#define T_ 2048
#define DM 1024
#define H_ 16
#define HD_ 64

typedef __attribute__((ext_vector_type(8))) short bf16x8v;
typedef __attribute__((ext_vector_type(4))) short short4v;
typedef __attribute__((ext_vector_type(4))) float f32x4;

__device__ __forceinline__ short f2bf(float f){
  unsigned u = __builtin_bit_cast(unsigned, f);
  u += 0x7fffu + ((u >> 16) & 1u);
  return (short)(u >> 16);
}
__device__ __forceinline__ float bf2f(short s){
  unsigned u = ((unsigned)(unsigned short)s) << 16;
  return __builtin_bit_cast(float, u);
}

#define GLOAD_LDS16(g, l) \
  __builtin_amdgcn_global_load_lds((const __attribute__((address_space(1))) unsigned int*)(g), \
                                   (__attribute__((address_space(3))) unsigned int*)(l), 16, 0, 0)

#define MFMA16(a, b, c) __builtin_amdgcn_mfma_f32_16x16x32_bf16((a), (b), (c), 0, 0, 0)

// ---------------------------------------------------------------------------
// fp32 -> bf16 conversion for 3 activations (4M elems) + 4 weights (1M elems)
// ---------------------------------------------------------------------------
__global__ __launch_bounds__(256) void conv_kernel(
    const float* __restrict__ s0, const float* __restrict__ s1, const float* __restrict__ s2,
    const float* __restrict__ s3, const float* __restrict__ s4, const float* __restrict__ s5,
    const float* __restrict__ s6,
    short* __restrict__ d0, short* __restrict__ d1, short* __restrict__ d2,
    short* __restrict__ d3, short* __restrict__ d4, short* __restrict__ d5,
    short* __restrict__ d6)
{
  int y = blockIdx.y;
  const float* s; short* d; int n;
  switch (y) {
    case 0: s = s0; d = d0; n = B_*T_*DM; break;
    case 1: s = s1; d = d1; n = B_*T_*DM; break;
    case 2: s = s2; d = d2; n = B_*T_*DM; break;
    case 3: s = s3; d = d3; n = DM*DM;   break;
    case 4: s = s4; d = d4; n = DM*DM;   break;
    case 5: s = s5; d = d5; n = DM*DM;   break;
    default: s = s6; d = d6; n = DM*DM;  break;
  }
  int i = (blockIdx.x * 256 + threadIdx.x) * 4;
  if (i >= n) return;
  float4 f = *(const float4*)(s + i);
  short4v o;
  o.x = f2bf(f.x); o.y = f2bf(f.y); o.z = f2bf(f.z); o.w = f2bf(f.w);
  *(short4v*)(d + i) = o;
}

// ---------------------------------------------------------------------------
// Projection GEMM: C = X(4096x1024) * W^T(1024x1024), bf16 MFMA, 128x128 tile.
// z=0: Q (scaled 1/8) -> [b,h,t,hd]; z=1: K -> [b,h,t,hd]; z=2: V -> [b,h,hd,t]
// ---------------------------------------------------------------------------
__global__ __launch_bounds__(256) void proj_gemm(
    const short* __restrict__ xq, const short* __restrict__ xk, const short* __restrict__ xv,
    const short* __restrict__ wq, const short* __restrict__ wk, const short* __restrict__ wv,
    short* __restrict__ qo, short* __restrict__ ko, short* __restrict__ vto)
{
  __shared__ short As[128 * 32];
  __shared__ short Bs[128 * 32];
  const int z = blockIdx.z;
  const short* A  = (z == 0) ? xq : (z == 1) ? xk : xv;
  const short* Bw = (z == 0) ? wq : (z == 1) ? wk : wv;
  const int m0 = blockIdx.x * 128;
  const int n0 = blockIdx.y * 128;
  const int tid = threadIdx.x;
  const int w = tid >> 6, l = tid & 63;
  const int wr = w >> 1, wc = w & 1;
  const int fr = l & 15, kq8 = (l >> 4) * 8;
  const int srow = tid >> 2, scol = (tid & 3) * 8;

  f32x4 acc[4][4] = {};

  for (int k0 = 0; k0 < DM; k0 += 32) {
    __syncthreads();
    GLOAD_LDS16(A  + (size_t)(m0 + srow) * DM + k0 + scol,      (char*)As + tid * 16);
    GLOAD_LDS16(A  + (size_t)(m0 + 64 + srow) * DM + k0 + scol, (char*)As + 4096 + tid * 16);
    GLOAD_LDS16(Bw + (size_t)(n0 + srow) * DM + k0 + scol,      (char*)Bs + tid * 16);
    GLOAD_LDS16(Bw + (size_t)(n0 + 64 + srow) * DM + k0 + scol, (char*)Bs + 4096 + tid * 16);
    __syncthreads();
    bf16x8v a[4], b[4];
#pragma unroll
    for (int i = 0; i < 4; i++) a[i] = *(const bf16x8v*)&As[(wr * 64 + i * 16 + fr) * 32 + kq8];
#pragma unroll
    for (int j = 0; j < 4; j++) b[j] = *(const bf16x8v*)&Bs[(wc * 64 + j * 16 + fr) * 32 + kq8];
#pragma unroll
    for (int i = 0; i < 4; i++)
#pragma unroll
      for (int j = 0; j < 4; j++)
        acc[i][j] = MFMA16(a[i], b[j], acc[i][j]);
  }

  const float scale = (z == 0) ? 0.125f : 1.0f;
  short* dst01 = (z == 0) ? qo : ko;
#pragma unroll
  for (int i = 0; i < 4; i++) {
#pragma unroll
    for (int j = 0; j < 4; j++) {
#pragma unroll
      for (int r = 0; r < 4; r++) {
        int row = m0 + wr * 64 + i * 16 + (l >> 4) * 4 + r;
        int col = n0 + wc * 64 + j * 16 + fr;
        int bb = row >> 11, tt = row & (T_ - 1);
        int hh = col >> 6,  hd = col & (HD_ - 1);
        short v = f2bf(acc[i][j][r] * scale);
        if (z == 2)
          vto[(((size_t)bb * H_ + hh) * HD_ + hd) * T_ + tt] = v;
        else
          dst01[(((size_t)bb * H_ + hh) * T_ + tt) * HD_ + hd] = v;
      }
    }
  }
}

// ---------------------------------------------------------------------------
// Column sums of V (for fully-masked rows): vs[bh*64+hd] = sum_t V[bh][t][hd]
// ---------------------------------------------------------------------------
__global__ __launch_bounds__(256) void vsum_kernel(const short* __restrict__ vt,
                                                   float* __restrict__ vs)
{
  __shared__ float red[256];
  int bh = blockIdx.x;
  int tid = threadIdx.x;
  int hd = tid & 63, part = tid >> 6;
  const short* src = vt + ((size_t)bh * HD_ + hd) * T_ + part * 512;
  float s = 0.f;
  for (int i = 0; i < 512; i += 4) {
    short4v v = *(const short4v*)(src + i);
    s += bf2f(v.x) + bf2f(v.y) + bf2f(v.z) + bf2f(v.w);
  }
  red[tid] = s;
  __syncthreads();
  if (part == 0)
    vs[(size_t)bh * HD_ + hd] = red[hd] + red[64 + hd] + red[128 + hd] + red[192 + hd];
}

// ---------------------------------------------------------------------------
// Attention v7: swapped-operand QK^T, two-pass flash, batch-fused,
// split-K across 4 waves (256 threads). Grid 2048 WGs.
// PV merged pairwise via LDS overlay; outh written by all 256 threads.
// ---------------------------------------------------------------------------
__global__ __launch_bounds__(256, 6) void attn_kernel(
    const short* __restrict__ qw, const short* __restrict__ kw, const short* __restrict__ vt,
    const float* __restrict__ bias, const int* __restrict__ mask,
    const int* __restrict__ causal_p, const float* __restrict__ vsum,
    float* __restrict__ attn_out, short* __restrict__ outh)
{
  __shared__ short p_l[4][2][16][68];   // per-wave bf16 p tiles (17.4 KB)
  __shared__ float ml_l[4][2][16][2];   // [wave][batch][row][{m,l}]
  __shared__ float mrow_l[2][16];       // merged max per [batch][row]
  float* pvbuf = (float*)&p_l[0][0][0][0]; // overlay: 2 x [2][16][64] f32 (16 KB)

  const int tid = threadIdx.x;
  const int w = tid >> 6, l = tid & 63;
  const int fr = l & 15, q4 = l >> 4, kq8 = q4 * 8;
  const int wgid = blockIdx.x;
  const int h  = (wgid & 7) | (((wgid >> 3) & 1) << 3);
  const int jt = 127 - (wgid >> 4);
  const int q0w = jt * 16;
  const int causal = *causal_p;
  const int L = causal ? (q0w + 16) : T_;
  const int KEND = (L + 63) & ~63;
  const float invT = 1.0f / (float)T_;
  const int qrow = q0w + fr;            // this lane's q-row (global)

  const short* Kb0 = kw + ((size_t)0 * H_ + h) * T_ * HD_;
  const short* Kb1 = kw + ((size_t)1 * H_ + h) * T_ * HD_;
  const short* Vb0 = vt + ((size_t)0 * H_ + h) * HD_ * T_;
  const short* Vb1 = vt + ((size_t)1 * H_ + h) * HD_ * T_;
  const float* brow = bias + ((size_t)h * T_ + qrow) * T_;

  bf16x8v qa[2][2];
#pragma unroll
  for (int b = 0; b < 2; b++) {
    const short* qp = qw + (((size_t)b * H_ + h) * T_ + qrow) * HD_;
    qa[b][0] = *(const bf16x8v*)(qp + kq8);
    qa[b][1] = *(const bf16x8v*)(qp + 32 + kq8);
  }

  float m_[2] = {-3e38f, -3e38f}, l_[2] = {0.f, 0.f};

  // ---------------- pass 1: chunk-batched online max/sum ----------------
  for (int k0 = w * 64; k0 < KEND; k0 += 256) {
    f32x4 sv[2][4];
#pragma unroll
    for (int t = 0; t < 4; t++) {
      const int kb = k0 + t * 16;
      const short* kp0 = Kb0 + (size_t)(kb + fr) * HD_ + kq8;
      const short* kp1 = Kb1 + (size_t)(kb + fr) * HD_ + kq8;
      f32x4 a0 = {0.f, 0.f, 0.f, 0.f}, a1 = {0.f, 0.f, 0.f, 0.f};
      a0 = MFMA16(*(const bf16x8v*)kp0,        qa[0][0], a0);
      a0 = MFMA16(*(const bf16x8v*)(kp0 + 32), qa[0][1], a0);
      a1 = MFMA16(*(const bf16x8v*)kp1,        qa[1][0], a1);
      a1 = MFMA16(*(const bf16x8v*)(kp1 + 32), qa[1][1], a1);
      f32x4 bi = *(const f32x4*)(brow + kb + q4 * 4);
      int4 mk0 = *(const int4*)(mask + kb + q4 * 4);
      int4 mk1 = *(const int4*)(mask + T_ + kb + q4 * 4);
      int mka[4] = {mk0.x, mk0.y, mk0.z, mk0.w};
      int mkb[4] = {mk1.x, mk1.y, mk1.z, mk1.w};
      if (!causal || (kb + 15 <= q0w)) {
#pragma unroll
        for (int r = 0; r < 4; r++) {
          sv[0][t][r] = mka[r] ? (a0[r] + bi[r]) : -1e9f;
          sv[1][t][r] = mkb[r] ? (a1[r] + bi[r]) : -1e9f;
        }
      } else {
#pragma unroll
        for (int r = 0; r < 4; r++) {
          bool cok = (kb + q4 * 4 + r) <= qrow;
          sv[0][t][r] = (mka[r] && cok) ? (a0[r] + bi[r]) : -1e9f;
          sv[1][t][r] = (mkb[r] && cok) ? (a1[r] + bi[r]) : -1e9f;
        }
      }
    }
#pragma unroll
    for (int b = 0; b < 2; b++) {
      float tm = -3e38f;
#pragma unroll
      for (int t = 0; t < 4; t++)
#pragma unroll
        for (int r = 0; r < 4; r++) tm = fmaxf(tm, sv[b][t][r]);
      float nm = fmaxf(m_[b], tm);
      float ss = 0.f;
#pragma unroll
      for (int t = 0; t < 4; t++)
#pragma unroll
        for (int r = 0; r < 4; r++) ss += __expf(sv[b][t][r] - nm);
      l_[b] = l_[b] * __expf(m_[b] - nm) + ss;
      m_[b] = nm;
    }
  }
  // combine the 4 q4 lane-groups (same q-row)
#pragma unroll
  for (int b = 0; b < 2; b++) {
#pragma unroll
    for (int off = 16; off < 64; off <<= 1) {
      float om = __shfl_xor(m_[b], off);
      float ol = __shfl_xor(l_[b], off);
      float nm = fmaxf(m_[b], om);
      l_[b] = l_[b] * __expf(m_[b] - nm) + ol * __expf(om - nm);
      m_[b] = nm;
    }
  }
  if (q4 == 0) {
#pragma unroll
    for (int b = 0; b < 2; b++) {
      ml_l[w][b][fr][0] = m_[b];
      ml_l[w][b][fr][1] = l_[b];
    }
  }
  __syncthreads();

  // merge across the four waves -> lse, fm (per lane's q-row fr)
  float lse[2];
  bool fm[2];
#pragma unroll
  for (int b = 0; b < 2; b++) {
    float M = ml_l[0][b][fr][0];
#pragma unroll
    for (int w2 = 1; w2 < 4; w2++) M = fmaxf(M, ml_l[w2][b][fr][0]);
    float lsum = 0.f;
#pragma unroll
    for (int w2 = 0; w2 < 4; w2++)
      lsum += ml_l[w2][b][fr][1] * __expf(ml_l[w2][b][fr][0] - M);
    fm[b] = (M <= -0.5e9f);
    lse[b] = M + __logf(lsum);
    if (q4 == 0 && w == 0) mrow_l[b][fr] = M;
  }

  // ---------------- pass 2: p, coalesced NT store, PV ----------------
  f32x4 oacc[2][4] = {};
  for (int k0 = w * 64; k0 < KEND; k0 += 256) {
#pragma unroll
    for (int t = 0; t < 4; t++) {
      const int kb = k0 + t * 16;
      const short* kp0 = Kb0 + (size_t)(kb + fr) * HD_ + kq8;
      const short* kp1 = Kb1 + (size_t)(kb + fr) * HD_ + kq8;
      f32x4 a0 = {0.f, 0.f, 0.f, 0.f}, a1 = {0.f, 0.f, 0.f, 0.f};
      a0 = MFMA16(*(const bf16x8v*)kp0,        qa[0][0], a0);
      a0 = MFMA16(*(const bf16x8v*)(kp0 + 32), qa[0][1], a0);
      a1 = MFMA16(*(const bf16x8v*)kp1,        qa[1][0], a1);
      a1 = MFMA16(*(const bf16x8v*)(kp1 + 32), qa[1][1], a1);
      f32x4 bi = *(const f32x4*)(brow + kb + q4 * 4);
      int4 mk0 = *(const int4*)(mask + kb + q4 * 4);
      int4 mk1 = *(const int4*)(mask + T_ + kb + q4 * 4);
      int mka[4] = {mk0.x, mk0.y, mk0.z, mk0.w};
      int mkb[4] = {mk1.x, mk1.y, mk1.z, mk1.w};
      f32x4 p0, p1;
      if (!causal || (kb + 15 <= q0w)) {
#pragma unroll
        for (int r = 0; r < 4; r++) {
          p0[r] = mka[r] ? __expf(a0[r] + bi[r] - lse[0]) : 0.f;
          p1[r] = mkb[r] ? __expf(a1[r] + bi[r] - lse[1]) : 0.f;
        }
      } else {
#pragma unroll
        for (int r = 0; r < 4; r++) {
          bool cok = (kb + q4 * 4 + r) <= qrow;
          p0[r] = (mka[r] && cok) ? __expf(a0[r] + bi[r] - lse[0]) : 0.f;
          p1[r] = (mkb[r] && cok) ? __expf(a1[r] + bi[r] - lse[1]) : 0.f;
        }
      }
      f32x4 st0, st1;
#pragma unroll
      for (int r = 0; r < 4; r++) {
        st0[r] = fm[0] ? invT : p0[r];
        st1[r] = fm[1] ? invT : p1[r];
      }
      __builtin_nontemporal_store(st0,
          (f32x4*)(attn_out + (((size_t)0 * H_ + h) * T_ + qrow) * T_ + kb + q4 * 4));
      __builtin_nontemporal_store(st1,
          (f32x4*)(attn_out + (((size_t)1 * H_ + h) * T_ + qrow) * T_ + kb + q4 * 4));
      short4v pb0, pb1;
#pragma unroll
      for (int r = 0; r < 4; r++) { pb0[r] = f2bf(p0[r]); pb1[r] = f2bf(p1[r]); }
      *(short4v*)&p_l[w][0][fr][t * 16 + q4 * 4] = pb0;
      *(short4v*)&p_l[w][1][fr][t * 16 + q4 * 4] = pb1;
    }
    // PV for this 64-col chunk
#pragma unroll
    for (int ks = 0; ks < 2; ks++) {
      bf16x8v pa0 = *(const bf16x8v*)&p_l[w][0][fr][ks * 32 + kq8];
      bf16x8v pa1 = *(const bf16x8v*)&p_l[w][1][fr][ks * 32 + kq8];
#pragma unroll
      for (int n0 = 0; n0 < 4; n0++) {
        bf16x8v vv0 = *(const bf16x8v*)&Vb0[(size_t)(n0 * 16 + fr) * T_ + k0 + ks * 32 + kq8];
        bf16x8v vv1 = *(const bf16x8v*)&Vb1[(size_t)(n0 * 16 + fr) * T_ + k0 + ks * 32 + kq8];
        oacc[0][n0] = MFMA16(pa0, vv0, oacc[0][n0]);
        oacc[1][n0] = MFMA16(pa1, vv1, oacc[1][n0]);
      }
    }
  }

  // ---------------- PV merge (pairwise via LDS overlay) ----------------
  __syncthreads();                      // all p_l reads done; overlay is safe
  if (w >= 2) {
    float* dst = pvbuf + (w - 2) * 2048;
#pragma unroll
    for (int b = 0; b < 2; b++)
#pragma unroll
      for (int n0 = 0; n0 < 4; n0++)
#pragma unroll
        for (int r = 0; r < 4; r++)
          dst[(b * 16 + q4 * 4 + r) * 64 + n0 * 16 + fr] = oacc[b][n0][r];
  }
  __syncthreads();
  if (w < 2) {
    float* dst = pvbuf + w * 2048;
#pragma unroll
    for (int b = 0; b < 2; b++)
#pragma unroll
      for (int n0 = 0; n0 < 4; n0++)
#pragma unroll
        for (int r = 0; r < 4; r++) {
          int idx = (b * 16 + q4 * 4 + r) * 64 + n0 * 16 + fr;
          dst[idx] += oacc[b][n0][r];
        }
  }
  __syncthreads();
  // final sum + fm override + outh write: 256 threads x 8 floats
  {
    int b = tid >> 7, row = (tid >> 3) & 15, c0 = (tid & 7) * 8;
    bool fmr = mrow_l[b][row] <= -0.5e9f;
    int base = (b * 16 + row) * 64 + c0;
    short4v o0, o1;
#pragma unroll
    for (int j = 0; j < 8; j++) {
      float val = pvbuf[base + j] + pvbuf[2048 + base + j];
      if (fmr) val = vsum[((size_t)b * H_ + h) * HD_ + c0 + j] * invT;
      if (j < 4) o0[j] = f2bf(val); else o1[j - 4] = f2bf(val);
    }
    short* op = outh + (((size_t)b * H_ + h) * T_ + q0w + row) * HD_ + c0;
    *(short4v*)op = o0;
    *(short4v*)(op + 4) = o1;
  }

  // ---------------- tail fill [KEND, T) (4 waves, split) ----------------
  if (KEND < T_) {
    float fill0 = fm[0] ? invT : 0.f;
    float fill1 = fm[1] ? invT : 0.f;
    f32x4 fv0 = {fill0, fill0, fill0, fill0};
    f32x4 fv1 = {fill1, fill1, fill1, fill1};
    float* r0 = attn_out + (((size_t)0 * H_ + h) * T_ + qrow) * T_;
    float* r1 = attn_out + (((size_t)1 * H_ + h) * T_ + qrow) * T_;
    for (int cb = KEND + w * 64; cb < T_; cb += 256) {
#pragma unroll
      for (int t = 0; t < 4; t++) {
        __builtin_nontemporal_store(fv0, (f32x4*)(r0 + cb + t * 16 + q4 * 4));
        __builtin_nontemporal_store(fv1, (f32x4*)(r1 + cb + t * 16 + q4 * 4));
      }
    }
  }
}

// ---------------------------------------------------------------------------
// Output GEMM: out = out_h(4096x1024 logical) * Wo^T, fp32 output
// ---------------------------------------------------------------------------
__global__ __launch_bounds__(256) void out_gemm(
    const short* __restrict__ Ah, const short* __restrict__ Bw, float* __restrict__ Co)
{
  __shared__ short As[128 * 32];
  __shared__ short Bs[128 * 32];
  const int m0 = blockIdx.x * 128;
  const int n0 = blockIdx.y * 128;
  const int tid = threadIdx.x;
  const int w = tid >> 6, l = tid & 63;
  const int wr = w >> 1, wc = w & 1;
  const int fr = l & 15, kq8 = (l >> 4) * 8;
  const int srow = tid >> 2, scol = (tid & 3) * 8;

  f32x4 acc[4][4] = {};

  for (int k0 = 0; k0 < DM; k0 += 32) {
    __syncthreads();
    int kk = k0 + scol;
    int hh = kk >> 6, hd = kk & 63;
    {
      int m1 = m0 + srow;
      const short* src1 = Ah + (((size_t)(m1 >> 11) * H_ + hh) * T_ + (m1 & (T_ - 1))) * HD_ + hd;
      GLOAD_LDS16(src1, (char*)As + tid * 16);
      int m2 = m0 + 64 + srow;
      const short* src2 = Ah + (((size_t)(m2 >> 11) * H_ + hh) * T_ + (m2 & (T_ - 1))) * HD_ + hd;
      GLOAD_LDS16(src2, (char*)As + 4096 + tid * 16);
    }
    GLOAD_LDS16(Bw + (size_t)(n0 + srow) * DM + kk,      (char*)Bs + tid * 16);
    GLOAD_LDS16(Bw + (size_t)(n0 + 64 + srow) * DM + kk, (char*)Bs + 4096 + tid * 16);
    __syncthreads();
    bf16x8v a[4], b[4];
#pragma unroll
    for (int i = 0; i < 4; i++) a[i] = *(const bf16x8v*)&As[(wr * 64 + i * 16 + fr) * 32 + kq8];
#pragma unroll
    for (int j = 0; j < 4; j++) b[j] = *(const bf16x8v*)&Bs[(wc * 64 + j * 16 + fr) * 32 + kq8];
#pragma unroll
    for (int i = 0; i < 4; i++)
#pragma unroll
      for (int j = 0; j < 4; j++)
        acc[i][j] = MFMA16(a[i], b[j], acc[i][j]);
  }

#pragma unroll
  for (int i = 0; i < 4; i++)
#pragma unroll
    for (int j = 0; j < 4; j++)
#pragma unroll
      for (int r = 0; r < 4; r++) {
        int row = m0 + wr * 64 + i * 16 + (l >> 4) * 4 + r;
        int col = n0 + wc * 64 + j * 16 + fr;
        Co[(size_t)row * DM + col] = acc[i][j][r];
      }
}

// ---------------------------------------------------------------------------
extern "C" void kernel_launch(void* const* d_in, const int* in_sizes, int n_in,
                              void* d_out, int out_size, void* d_ws, size_t ws_size,
                              hipStream_t stream)
{
  const float* x_q  = (const float*)d_in[0];
  const float* x_k  = (const float*)d_in[1];
  const float* x_v  = (const float*)d_in[2];
  const int*   mask = (const int*)d_in[3];
  const int*   causal = (const int*)d_in[4];
  const float* bias = (const float*)d_in[5];
  const float* Wq   = (const float*)d_in[6];
  const float* Wk   = (const float*)d_in[7];
  const float* Wv   = (const float*)d_in[8];
  const float* Wo   = (const float*)d_in[9];

  char* ws = (char*)d_ws;
  const size_t XB = (size_t)B_ * T_ * DM * 2;   // 8 MB
  const size_t WB = (size_t)DM * DM * 2;        // 2 MB
  short* xq_b = (short*)(ws + 0 * XB);
  short* xk_b = (short*)(ws + 1 * XB);
  short* xv_b = (short*)(ws + 2 * XB);
  short* wq_b = (short*)(ws + 3 * XB + 0 * WB);
  short* wk_b = (short*)(ws + 3 * XB + 1 * WB);
  short* wv_b = (short*)(ws + 3 * XB + 2 * WB);
  short* wo_b = (short*)(ws + 3 * XB + 3 * WB);
  short* q_ws  = (short*)(ws + 3 * XB + 4 * WB);
  short* k_ws  = (short*)(ws + 4 * XB + 4 * WB);
  short* vt_ws = (short*)(ws + 5 * XB + 4 * WB);
  short* oh_ws = (short*)(ws + 6 * XB + 4 * WB);
  float* vs_ws = (float*)(ws + 7 * XB + 4 * WB);

  float* out0 = (float*)d_out;
  float* attn = out0 + (size_t)B_ * T_ * DM;

  conv_kernel<<<dim3(4096, 7, 1), 256, 0, stream>>>(
      x_q, x_k, x_v, Wq, Wk, Wv, Wo,
      xq_b, xk_b, xv_b, wq_b, wk_b, wv_b, wo_b);

  proj_gemm<<<dim3(32, 8, 3), 256, 0, stream>>>(
      xq_b, xk_b, xv_b, wq_b, wk_b, wv_b, q_ws, k_ws, vt_ws);

  vsum_kernel<<<dim3(32, 1, 1), 256, 0, stream>>>(vt_ws, vs_ws);

  attn_kernel<<<dim3(2048, 1, 1), 256, 0, stream>>>(
      q_ws, k_ws, vt_ws, bias, mask, causal, vs_ws, attn, oh_ws);

  out_gemm<<<dim3(32, 8, 1), 256, 0, stream>>>(oh_ws, wo_b, out0);
}

// Round 8
// 467.533 us; speedup vs baseline: 1.4698x; 1.4698x over previous
//
#include <hip/hip_runtime.h>
#include <hip/hip_bf16.h>
#include <hip/hip_fp16.h>

#define B_ 2
#define T_ 2048
#define DM 1024
#define H_ 16
#define HD_ 64

typedef __attribute__((ext_vector_type(8))) short bf16x8v;
typedef __attribute__((ext_vector_type(4))) short short4v;
typedef __attribute__((ext_vector_type(4))) float f32x4;

__device__ __forceinline__ short f2bf(float f){
  unsigned u = __builtin_bit_cast(unsigned, f);
  u += 0x7fffu + ((u >> 16) & 1u);
  return (short)(u >> 16);
}
__device__ __forceinline__ float bf2f(short s){
  unsigned u = ((unsigned)(unsigned short)s) << 16;
  return __builtin_bit_cast(float, u);
}

#define GLOAD_LDS16(g, l) \
  __builtin_amdgcn_global_load_lds((const __attribute__((address_space(1))) unsigned int*)(g), \
                                   (__attribute__((address_space(3))) unsigned int*)(l), 16, 0, 0)

#define MFMA16(a, b, c) __builtin_amdgcn_mfma_f32_16x16x32_bf16((a), (b), (c), 0, 0, 0)

// ---------------------------------------------------------------------------
// fp32 -> bf16 conversion for 3 activations (4M elems) + 4 weights (1M elems)
// ---------------------------------------------------------------------------
__global__ __launch_bounds__(256) void conv_kernel(
    const float* __restrict__ s0, const float* __restrict__ s1, const float* __restrict__ s2,
    const float* __restrict__ s3, const float* __restrict__ s4, const float* __restrict__ s5,
    const float* __restrict__ s6,
    short* __restrict__ d0, short* __restrict__ d1, short* __restrict__ d2,
    short* __restrict__ d3, short* __restrict__ d4, short* __restrict__ d5,
    short* __restrict__ d6)
{
  int y = blockIdx.y;
  const float* s; short* d; int n;
  switch (y) {
    case 0: s = s0; d = d0; n = B_*T_*DM; break;
    case 1: s = s1; d = d1; n = B_*T_*DM; break;
    case 2: s = s2; d = d2; n = B_*T_*DM; break;
    case 3: s = s3; d = d3; n = DM*DM;   break;
    case 4: s = s4; d = d4; n = DM*DM;   break;
    case 5: s = s5; d = d5; n = DM*DM;   break;
    default: s = s6; d = d6; n = DM*DM;  break;
  }
  int i = (blockIdx.x * 256 + threadIdx.x) * 4;
  if (i >= n) return;
  float4 f = *(const float4*)(s + i);
  short4v o;
  o.x = f2bf(f.x); o.y = f2bf(f.y); o.z = f2bf(f.z); o.w = f2bf(f.w);
  *(short4v*)(d + i) = o;
}

// ---------------------------------------------------------------------------
// Projection GEMM: C = X(4096x1024) * W^T(1024x1024), bf16 MFMA, 128x128 tile.
// z=0: Q (scaled 1/8) -> [b,h,t,hd]; z=1: K -> [b,h,t,hd]; z=2: V -> [b,h,hd,t]
// ---------------------------------------------------------------------------
__global__ __launch_bounds__(256) void proj_gemm(
    const short* __restrict__ xq, const short* __restrict__ xk, const short* __restrict__ xv,
    const short* __restrict__ wq, const short* __restrict__ wk, const short* __restrict__ wv,
    short* __restrict__ qo, short* __restrict__ ko, short* __restrict__ vto)
{
  __shared__ short As[128 * 32];
  __shared__ short Bs[128 * 32];
  const int z = blockIdx.z;
  const short* A  = (z == 0) ? xq : (z == 1) ? xk : xv;
  const short* Bw = (z == 0) ? wq : (z == 1) ? wk : wv;
  const int m0 = blockIdx.x * 128;
  const int n0 = blockIdx.y * 128;
  const int tid = threadIdx.x;
  const int w = tid >> 6, l = tid & 63;
  const int wr = w >> 1, wc = w & 1;
  const int fr = l & 15, kq8 = (l >> 4) * 8;
  const int srow = tid >> 2, scol = (tid & 3) * 8;

  f32x4 acc[4][4] = {};

  for (int k0 = 0; k0 < DM; k0 += 32) {
    __syncthreads();
    GLOAD_LDS16(A  + (size_t)(m0 + srow) * DM + k0 + scol,      (char*)As + tid * 16);
    GLOAD_LDS16(A  + (size_t)(m0 + 64 + srow) * DM + k0 + scol, (char*)As + 4096 + tid * 16);
    GLOAD_LDS16(Bw + (size_t)(n0 + srow) * DM + k0 + scol,      (char*)Bs + tid * 16);
    GLOAD_LDS16(Bw + (size_t)(n0 + 64 + srow) * DM + k0 + scol, (char*)Bs + 4096 + tid * 16);
    __syncthreads();
    bf16x8v a[4], b[4];
#pragma unroll
    for (int i = 0; i < 4; i++) a[i] = *(const bf16x8v*)&As[(wr * 64 + i * 16 + fr) * 32 + kq8];
#pragma unroll
    for (int j = 0; j < 4; j++) b[j] = *(const bf16x8v*)&Bs[(wc * 64 + j * 16 + fr) * 32 + kq8];
#pragma unroll
    for (int i = 0; i < 4; i++)
#pragma unroll
      for (int j = 0; j < 4; j++)
        acc[i][j] = MFMA16(a[i], b[j], acc[i][j]);
  }

  const float scale = (z == 0) ? 0.125f : 1.0f;
  short* dst01 = (z == 0) ? qo : ko;
#pragma unroll
  for (int i = 0; i < 4; i++) {
#pragma unroll
    for (int j = 0; j < 4; j++) {
#pragma unroll
      for (int r = 0; r < 4; r++) {
        int row = m0 + wr * 64 + i * 16 + (l >> 4) * 4 + r;
        int col = n0 + wc * 64 + j * 16 + fr;
        int bb = row >> 11, tt = row & (T_ - 1);
        int hh = col >> 6,  hd = col & (HD_ - 1);
        short v = f2bf(acc[i][j][r] * scale);
        if (z == 2)
          vto[(((size_t)bb * H_ + hh) * HD_ + hd) * T_ + tt] = v;
        else
          dst01[(((size_t)bb * H_ + hh) * T_ + tt) * HD_ + hd] = v;
      }
    }
  }
}

// ---------------------------------------------------------------------------
// Column sums of V (for fully-masked rows): vs[bh*64+hd] = sum_t V[bh][t][hd]
// ---------------------------------------------------------------------------
__global__ __launch_bounds__(256) void vsum_kernel(const short* __restrict__ vt,
                                                   float* __restrict__ vs)
{
  __shared__ float red[256];
  int bh = blockIdx.x;
  int tid = threadIdx.x;
  int hd = tid & 63, part = tid >> 6;
  const short* src = vt + ((size_t)bh * HD_ + hd) * T_ + part * 512;
  float s = 0.f;
  for (int i = 0; i < 512; i += 4) {
    short4v v = *(const short4v*)(src + i);
    s += bf2f(v.x) + bf2f(v.y) + bf2f(v.z) + bf2f(v.w);
  }
  red[tid] = s;
  __syncthreads();
  if (part == 0)
    vs[(size_t)bh * HD_ + hd] = red[hd] + red[64 + hd] + red[128 + hd] + red[192 + hd];
}

// ---------------------------------------------------------------------------
// Attention v8 = v6 (swapped QK^T, two-pass, batch-fused, split-K 2 waves)
// + uniform load balance: each WG owns TWO 8-row q-tiles paired so total
// work is constant: A at q0A=8j (light), B at q0B=8(255-j) (heavy).
// Lanes fr<8 -> A rows, fr>=8 -> B rows. K-loop runs to KEND(L_B); A-rows
// beyond L_A are causally masked (store 0 = their tail). Bias loads
// predicated on kb<=qrow. Grid 2048 x 128 threads.
// ---------------------------------------------------------------------------
__global__ __launch_bounds__(128, 4) void attn_kernel(
    const short* __restrict__ qw, const short* __restrict__ kw, const short* __restrict__ vt,
    const float* __restrict__ bias, const int* __restrict__ mask,
    const int* __restrict__ causal_p, const float* __restrict__ vsum,
    float* __restrict__ attn_out, short* __restrict__ outh)
{
  __shared__ short p_l[2][2][16][68];   // [wave][batch][row][k] bf16 p-tile (padded)
  __shared__ float ml_l[2][2][16][2];   // [wave][batch][row][{m,l}]
  __shared__ float mrow_l[2][16];       // merged max per [batch][row]
  float* pv = (float*)&p_l[0][0][0][0]; // overlay after barrier: [2][16][64] f32

  const int tid = threadIdx.x;
  const int w = tid >> 6, l = tid & 63;
  const int fr = l & 15, q4 = l >> 4, kq8 = q4 * 8;
  const int wgid = blockIdx.x;
  const int h  = (wgid & 7) | (((wgid >> 3) & 1) << 3);
  const int jA = wgid >> 4;             // 0..127
  const int q0A = jA * 8;
  const int q0B = (255 - jA) * 8;
  const int causal = *causal_p;
  const int LB = q0B + 8;
  const int KEND = causal ? ((LB + 63) & ~63) : T_;
  const float invT = 1.0f / (float)T_;
  const int qrow = (fr < 8) ? (q0A + fr) : (q0B + fr - 8);  // this lane's q-row

  const short* Kb0 = kw + ((size_t)0 * H_ + h) * T_ * HD_;
  const short* Kb1 = kw + ((size_t)1 * H_ + h) * T_ * HD_;
  const short* Vb0 = vt + ((size_t)0 * H_ + h) * HD_ * T_;
  const short* Vb1 = vt + ((size_t)1 * H_ + h) * HD_ * T_;
  const float* brow = bias + ((size_t)h * T_ + qrow) * T_;

  bf16x8v qa[2][2];
#pragma unroll
  for (int b = 0; b < 2; b++) {
    const short* qp = qw + (((size_t)b * H_ + h) * T_ + qrow) * HD_;
    qa[b][0] = *(const bf16x8v*)(qp + kq8);
    qa[b][1] = *(const bf16x8v*)(qp + 32 + kq8);
  }

  float m_[2] = {-3e38f, -3e38f}, l_[2] = {0.f, 0.f};

  // ---------------- pass 1: chunk-batched online max/sum ----------------
  for (int k0 = w * 64; k0 < KEND; k0 += 128) {
    f32x4 sv[2][4];
#pragma unroll
    for (int t = 0; t < 4; t++) {
      const int kb = k0 + t * 16;
      const short* kp0 = Kb0 + (size_t)(kb + fr) * HD_ + kq8;
      const short* kp1 = Kb1 + (size_t)(kb + fr) * HD_ + kq8;
      f32x4 a0 = {0.f, 0.f, 0.f, 0.f}, a1 = {0.f, 0.f, 0.f, 0.f};
      a0 = MFMA16(*(const bf16x8v*)kp0,        qa[0][0], a0);
      a0 = MFMA16(*(const bf16x8v*)(kp0 + 32), qa[0][1], a0);
      a1 = MFMA16(*(const bf16x8v*)kp1,        qa[1][0], a1);
      a1 = MFMA16(*(const bf16x8v*)(kp1 + 32), qa[1][1], a1);
      f32x4 bi = {0.f, 0.f, 0.f, 0.f};
      if (!causal || (kb + q4 * 4 <= qrow))
        bi = *(const f32x4*)(brow + kb + q4 * 4);
      int4 mk0 = *(const int4*)(mask + kb + q4 * 4);
      int4 mk1 = *(const int4*)(mask + T_ + kb + q4 * 4);
      int mka[4] = {mk0.x, mk0.y, mk0.z, mk0.w};
      int mkb[4] = {mk1.x, mk1.y, mk1.z, mk1.w};
#pragma unroll
      for (int r = 0; r < 4; r++) {
        bool cok = (!causal) || ((kb + q4 * 4 + r) <= qrow);
        sv[0][t][r] = (mka[r] && cok) ? (a0[r] + bi[r]) : -1e9f;
        sv[1][t][r] = (mkb[r] && cok) ? (a1[r] + bi[r]) : -1e9f;
      }
    }
#pragma unroll
    for (int b = 0; b < 2; b++) {
      float tm = -3e38f;
#pragma unroll
      for (int t = 0; t < 4; t++)
#pragma unroll
        for (int r = 0; r < 4; r++) tm = fmaxf(tm, sv[b][t][r]);
      float nm = fmaxf(m_[b], tm);
      float ss = 0.f;
#pragma unroll
      for (int t = 0; t < 4; t++)
#pragma unroll
        for (int r = 0; r < 4; r++) ss += __expf(sv[b][t][r] - nm);
      l_[b] = l_[b] * __expf(m_[b] - nm) + ss;
      m_[b] = nm;
    }
  }
  // combine the 4 q4 lane-groups (same q-row)
#pragma unroll
  for (int b = 0; b < 2; b++) {
#pragma unroll
    for (int off = 16; off < 64; off <<= 1) {
      float om = __shfl_xor(m_[b], off);
      float ol = __shfl_xor(l_[b], off);
      float nm = fmaxf(m_[b], om);
      l_[b] = l_[b] * __expf(m_[b] - nm) + ol * __expf(om - nm);
      m_[b] = nm;
    }
  }
  if (q4 == 0) {
#pragma unroll
    for (int b = 0; b < 2; b++) {
      ml_l[w][b][fr][0] = m_[b];
      ml_l[w][b][fr][1] = l_[b];
    }
  }
  __syncthreads();

  // merge across the two waves -> lse, fm (per lane's q-row fr)
  float lse[2];
  bool fm[2];
#pragma unroll
  for (int b = 0; b < 2; b++) {
    float ma = ml_l[0][b][fr][0], la = ml_l[0][b][fr][1];
    float mb = ml_l[1][b][fr][0], lb = ml_l[1][b][fr][1];
    float M = fmaxf(ma, mb);
    float lsum = la * __expf(ma - M) + lb * __expf(mb - M);
    fm[b] = (M <= -0.5e9f);
    lse[b] = M + __logf(lsum);
    if (q4 == 0 && w == 0) mrow_l[b][fr] = M;
  }

  // ---------------- pass 2: p, coalesced NT store, PV ----------------
  f32x4 oacc[2][4] = {};
  for (int k0 = w * 64; k0 < KEND; k0 += 128) {
#pragma unroll
    for (int t = 0; t < 4; t++) {
      const int kb = k0 + t * 16;
      const short* kp0 = Kb0 + (size_t)(kb + fr) * HD_ + kq8;
      const short* kp1 = Kb1 + (size_t)(kb + fr) * HD_ + kq8;
      f32x4 a0 = {0.f, 0.f, 0.f, 0.f}, a1 = {0.f, 0.f, 0.f, 0.f};
      a0 = MFMA16(*(const bf16x8v*)kp0,        qa[0][0], a0);
      a0 = MFMA16(*(const bf16x8v*)(kp0 + 32), qa[0][1], a0);
      a1 = MFMA16(*(const bf16x8v*)kp1,        qa[1][0], a1);
      a1 = MFMA16(*(const bf16x8v*)(kp1 + 32), qa[1][1], a1);
      f32x4 bi = {0.f, 0.f, 0.f, 0.f};
      if (!causal || (kb + q4 * 4 <= qrow))
        bi = *(const f32x4*)(brow + kb + q4 * 4);
      int4 mk0 = *(const int4*)(mask + kb + q4 * 4);
      int4 mk1 = *(const int4*)(mask + T_ + kb + q4 * 4);
      int mka[4] = {mk0.x, mk0.y, mk0.z, mk0.w};
      int mkb[4] = {mk1.x, mk1.y, mk1.z, mk1.w};
      f32x4 p0, p1;
#pragma unroll
      for (int r = 0; r < 4; r++) {
        bool cok = (!causal) || ((kb + q4 * 4 + r) <= qrow);
        p0[r] = (mka[r] && cok) ? __expf(a0[r] + bi[r] - lse[0]) : 0.f;
        p1[r] = (mkb[r] && cok) ? __expf(a1[r] + bi[r] - lse[1]) : 0.f;
      }
      f32x4 st0, st1;
#pragma unroll
      for (int r = 0; r < 4; r++) {
        st0[r] = fm[0] ? invT : p0[r];
        st1[r] = fm[1] ? invT : p1[r];
      }
      __builtin_nontemporal_store(st0,
          (f32x4*)(attn_out + (((size_t)0 * H_ + h) * T_ + qrow) * T_ + kb + q4 * 4));
      __builtin_nontemporal_store(st1,
          (f32x4*)(attn_out + (((size_t)1 * H_ + h) * T_ + qrow) * T_ + kb + q4 * 4));
      short4v pb0, pb1;
#pragma unroll
      for (int r = 0; r < 4; r++) { pb0[r] = f2bf(p0[r]); pb1[r] = f2bf(p1[r]); }
      *(short4v*)&p_l[w][0][fr][t * 16 + q4 * 4] = pb0;
      *(short4v*)&p_l[w][1][fr][t * 16 + q4 * 4] = pb1;
    }
    // PV for this 64-col chunk
#pragma unroll
    for (int ks = 0; ks < 2; ks++) {
      bf16x8v pa0 = *(const bf16x8v*)&p_l[w][0][fr][ks * 32 + kq8];
      bf16x8v pa1 = *(const bf16x8v*)&p_l[w][1][fr][ks * 32 + kq8];
#pragma unroll
      for (int n0 = 0; n0 < 4; n0++) {
        bf16x8v vv0 = *(const bf16x8v*)&Vb0[(size_t)(n0 * 16 + fr) * T_ + k0 + ks * 32 + kq8];
        bf16x8v vv1 = *(const bf16x8v*)&Vb1[(size_t)(n0 * 16 + fr) * T_ + k0 + ks * 32 + kq8];
        oacc[0][n0] = MFMA16(pa0, vv0, oacc[0][n0]);
        oacc[1][n0] = MFMA16(pa1, vv1, oacc[1][n0]);
      }
    }
  }

  // ---------------- PV merge (LDS overlay) + outh ----------------
  __syncthreads();                      // everyone done with p_l
  if (w == 0) {
#pragma unroll
    for (int b = 0; b < 2; b++)
#pragma unroll
      for (int n0 = 0; n0 < 4; n0++)
#pragma unroll
        for (int r = 0; r < 4; r++)
          pv[(b * 16 + q4 * 4 + r) * 64 + n0 * 16 + fr] = oacc[b][n0][r];
  }
  __syncthreads();
  if (w == 1) {
#pragma unroll
    for (int b = 0; b < 2; b++)
#pragma unroll
      for (int n0 = 0; n0 < 4; n0++)
#pragma unroll
        for (int r = 0; r < 4; r++) {
          int row = q4 * 4 + r, col = n0 * 16 + fr;
          int qg = (row < 8) ? (q0A + row) : (q0B + row - 8);
          float val = oacc[b][n0][r] + pv[(b * 16 + row) * 64 + col];
          if (mrow_l[b][row] <= -0.5e9f)
            val = vsum[((size_t)b * H_ + h) * HD_ + col] * invT;
          outh[(((size_t)b * H_ + h) * T_ + qg) * HD_ + col] = f2bf(val);
        }
  }

  // ---------------- tail fill [KEND, T) (both waves, split) ----------------
  if (KEND < T_) {
    float fill0 = fm[0] ? invT : 0.f;
    float fill1 = fm[1] ? invT : 0.f;
    f32x4 fv0 = {fill0, fill0, fill0, fill0};
    f32x4 fv1 = {fill1, fill1, fill1, fill1};
    float* r0 = attn_out + (((size_t)0 * H_ + h) * T_ + qrow) * T_;
    float* r1 = attn_out + (((size_t)1 * H_ + h) * T_ + qrow) * T_;
    for (int cb = KEND + w * 64; cb < T_; cb += 128) {
#pragma unroll
      for (int t = 0; t < 4; t++) {
        __builtin_nontemporal_store(fv0, (f32x4*)(r0 + cb + t * 16 + q4 * 4));
        __builtin_nontemporal_store(fv1, (f32x4*)(r1 + cb + t * 16 + q4 * 4));
      }
    }
  }
}

// ---------------------------------------------------------------------------
// Output GEMM: out = out_h(4096x1024 logical) * Wo^T, fp32 output
// ---------------------------------------------------------------------------
__global__ __launch_bounds__(256) void out_gemm(
    const short* __restrict__ Ah, const short* __restrict__ Bw, float* __restrict__ Co)
{
  __shared__ short As[128 * 32];
  __shared__ short Bs[128 * 32];
  const int m0 = blockIdx.x * 128;
  const int n0 = blockIdx.y * 128;
  const int tid = threadIdx.x;
  const int w = tid >> 6, l = tid & 63;
  const int wr = w >> 1, wc = w & 1;
  const int fr = l & 15, kq8 = (l >> 4) * 8;
  const int srow = tid >> 2, scol = (tid & 3) * 8;

  f32x4 acc[4][4] = {};

  for (int k0 = 0; k0 < DM; k0 += 32) {
    __syncthreads();
    int kk = k0 + scol;
    int hh = kk >> 6, hd = kk & 63;
    {
      int m1 = m0 + srow;
      const short* src1 = Ah + (((size_t)(m1 >> 11) * H_ + hh) * T_ + (m1 & (T_ - 1))) * HD_ + hd;
      GLOAD_LDS16(src1, (char*)As + tid * 16);
      int m2 = m0 + 64 + srow;
      const short* src2 = Ah + (((size_t)(m2 >> 11) * H_ + hh) * T_ + (m2 & (T_ - 1))) * HD_ + hd;
      GLOAD_LDS16(src2, (char*)As + 4096 + tid * 16);
    }
    GLOAD_LDS16(Bw + (size_t)(n0 + srow) * DM + kk,      (char*)Bs + tid * 16);
    GLOAD_LDS16(Bw + (size_t)(n0 + 64 + srow) * DM + kk, (char*)Bs + 4096 + tid * 16);
    __syncthreads();
    bf16x8v a[4], b[4];
#pragma unroll
    for (int i = 0; i < 4; i++) a[i] = *(const bf16x8v*)&As[(wr * 64 + i * 16 + fr) * 32 + kq8];
#pragma unroll
    for (int j = 0; j < 4; j++) b[j] = *(const bf16x8v*)&Bs[(wc * 64 + j * 16 + fr) * 32 + kq8];
#pragma unroll
    for (int i = 0; i < 4; i++)
#pragma unroll
      for (int j = 0; j < 4; j++)
        acc[i][j] = MFMA16(a[i], b[j], acc[i][j]);
  }

#pragma unroll
  for (int i = 0; i < 4; i++)
#pragma unroll
    for (int j = 0; j < 4; j++)
#pragma unroll
      for (int r = 0; r < 4; r++) {
        int row = m0 + wr * 64 + i * 16 + (l >> 4) * 4 + r;
        int col = n0 + wc * 64 + j * 16 + fr;
        Co[(size_t)row * DM + col] = acc[i][j][r];
      }
}

// ---------------------------------------------------------------------------
extern "C" void kernel_launch(void* const* d_in, const int* in_sizes, int n_in,
                              void* d_out, int out_size, void* d_ws, size_t ws_size,
                              hipStream_t stream)
{
  const float* x_q  = (const float*)d_in[0];
  const float* x_k  = (const float*)d_in[1];
  const float* x_v  = (const float*)d_in[2];
  const int*   mask = (const int*)d_in[3];
  const int*   causal = (const int*)d_in[4];
  const float* bias = (const float*)d_in[5];
  const float* Wq   = (const float*)d_in[6];
  const float* Wk   = (const float*)d_in[7];
  const float* Wv   = (const float*)d_in[8];
  const float* Wo   = (const float*)d_in[9];

  char* ws = (char*)d_ws;
  const size_t XB = (size_t)B_ * T_ * DM * 2;   // 8 MB
  const size_t WB = (size_t)DM * DM * 2;        // 2 MB
  short* xq_b = (short*)(ws + 0 * XB);
  short* xk_b = (short*)(ws + 1 * XB);
  short* xv_b = (short*)(ws + 2 * XB);
  short* wq_b = (short*)(ws + 3 * XB + 0 * WB);
  short* wk_b = (short*)(ws + 3 * XB + 1 * WB);
  short* wv_b = (short*)(ws + 3 * XB + 2 * WB);
  short* wo_b = (short*)(ws + 3 * XB + 3 * WB);
  short* q_ws  = (short*)(ws + 3 * XB + 4 * WB);
  short* k_ws  = (short*)(ws + 4 * XB + 4 * WB);
  short* vt_ws = (short*)(ws + 5 * XB + 4 * WB);
  short* oh_ws = (short*)(ws + 6 * XB + 4 * WB);
  float* vs_ws = (float*)(ws + 7 * XB + 4 * WB);

  float* out0 = (float*)d_out;
  float* attn = out0 + (size_t)B_ * T_ * DM;

  conv_kernel<<<dim3(4096, 7, 1), 256, 0, stream>>>(
      x_q, x_k, x_v, Wq, Wk, Wv, Wo,
      xq_b, xk_b, xv_b, wq_b, wk_b, wv_b, wo_b);

  proj_gemm<<<dim3(32, 8, 3), 256, 0, stream>>>(
      xq_b, xk_b, xv_b, wq_b, wk_b, wv_b, q_ws, k_ws, vt_ws);

  vsum_kernel<<<dim3(32, 1, 1), 256, 0, stream>>>(vt_ws, vs_ws);

  attn_kernel<<<dim3(2048, 1, 1), 128, 0, stream>>>(
      q_ws, k_ws, vt_ws, bias, mask, causal, vs_ws, attn, oh_ws);

  out_gemm<<<dim3(32, 8, 1), 256, 0, stream>>>(oh_ws, wo_b, out0);
}